// Round 1
// baseline (29.356 us; speedup 1.0000x reference)
//
#include <hip/hip_runtime.h>

#define AS1 __attribute__((address_space(1)))
#define AS3 __attribute__((address_space(3)))

typedef unsigned short u16;
typedef __bf16 bf16x8 __attribute__((ext_vector_type(8)));
typedef float f32x4 __attribute__((ext_vector_type(4)));

// ws layout (20 MB total):
//   A: [4][512][1024]  bf16(u16)  @ 0       (4 MB)   A[seg][b][i] = b_seg(x[b][i])
//   W: [4][1024][1024] bf16(u16)  @ 4 MB    (8 MB)   W[seg][o][i] = bf16(cp_seg[o][i])
//   P: [4][512][1024]  f32        @ 12 MB   (8 MB)   split-K partials

__device__ __forceinline__ u16 f2bf(float f) {
    union { float f; unsigned int u; } v;
    v.f = f;
    unsigned int u = v.u;
    u += 0x7fffu + ((u >> 16) & 1u);   // RNE
    return (u16)(u >> 16);
}

__global__ __launch_bounds__(256) void prep_kernel(
    const float* __restrict__ x,
    const float* __restrict__ cp0, const float* __restrict__ cp1,
    const float* __restrict__ cp2, const float* __restrict__ cp3,
    u16* __restrict__ A, u16* __restrict__ W)
{
    const int bid = blockIdx.x;
    const int tid = threadIdx.x;
    if (bid < 1024) {
        // W conversion: each thread converts the same float4 offset in all 4 cps
        const int idx = (bid * 256 + tid) * 4;            // [0, 1048576)
        const float* cps[4] = {cp0, cp1, cp2, cp3};
        #pragma unroll
        for (int seg = 0; seg < 4; ++seg) {
            float4 v = *(const float4*)(cps[seg] + idx);
            ushort4 o;
            o.x = f2bf(v.x); o.y = f2bf(v.y); o.z = f2bf(v.z); o.w = f2bf(v.w);
            *(ushort4*)(W + seg * 1048576 + idx) = o;
        }
    } else {
        // A computation: Bernstein weights times x
        const int idx = ((bid - 1024) * 256 + tid) * 4;   // [0, 524288)
        float4 v = *(const float4*)(x + idx);
        float vv[4] = {v.x, v.y, v.z, v.w};
        u16 q[4][4];
        #pragma unroll
        for (int j = 0; j < 4; ++j) {
            float xx = vv[j];
            float t = fminf(fabsf(xx), 1.0f);
            float s = 1.0f - t;
            q[0][j] = f2bf(s * s * s * xx);
            q[1][j] = f2bf(3.0f * s * s * t * xx);
            q[2][j] = f2bf(3.0f * s * t * t * xx);
            q[3][j] = f2bf(t * t * t * xx);
        }
        #pragma unroll
        for (int seg = 0; seg < 4; ++seg) {
            ushort4 o; o.x = q[seg][0]; o.y = q[seg][1]; o.z = q[seg][2]; o.w = q[seg][3];
            *(ushort4*)(A + seg * 524288 + idx) = o;
        }
    }
}

__device__ __forceinline__ void load16(const u16* g, u16* l) {
    __builtin_amdgcn_global_load_lds((const AS1 unsigned int*)g,
                                     (AS3 unsigned int*)l, 16, 0, 0);
}

// Split-K GEMM: one 64x64 output tile over K=1024 (one Bernstein segment) per WG.
// A (M x K) bf16 row-major, W (N x K) bf16 row-major ("B^T" form), P partial f32.
__global__ __launch_bounds__(256) void gemm_kernel(
    const u16* __restrict__ A, const u16* __restrict__ W,
    float* __restrict__ P)
{
    __shared__ u16 lsA[64 * 64];   // [row][k], 128 B row stride
    __shared__ u16 lsB[64 * 64];

    const int tid  = threadIdx.x;
    const int lane = tid & 63;
    const int wid  = tid >> 6;
    const int seg  = blockIdx.z;
    const int brow = blockIdx.y * 64;   // batch rows
    const int bcol = blockIdx.x * 64;   // out features

    const u16* Aseg = A + seg * 524288  + brow * 1024;
    const u16* Wseg = W + seg * 1048576 + bcol * 1024;

    // staging: 512 chunks of 16 B per tile; chunk c -> row c>>3, elem col (c&7)*8
    const int c0 = tid, c1 = tid + 256;
    const int r0 = c0 >> 3, e0 = (c0 & 7) * 8;
    const int r1 = c1 >> 3, e1 = (c1 & 7) * 8;

    // wave sub-tile: 2x2 wave grid, each wave 32x32
    const int wr = (wid >> 1) * 32;
    const int wc = (wid & 1) * 32;
    const int fr = lane & 15;             // fragment row/col
    const int fk = (lane >> 4) * 16;      // byte offset of k-group

    f32x4 acc[2][2] = {};

    for (int kt = 0; kt < 16; ++kt) {
        const int k0 = kt * 64;
        load16(Aseg + r0 * 1024 + k0 + e0, lsA + c0 * 8);
        load16(Aseg + r1 * 1024 + k0 + e1, lsA + c1 * 8);
        load16(Wseg + r0 * 1024 + k0 + e0, lsB + c0 * 8);
        load16(Wseg + r1 * 1024 + k0 + e1, lsB + c1 * 8);
        __syncthreads();   // compiler drains vmcnt before s_barrier

        const char* baseA = (const char*)lsA;
        const char* baseB = (const char*)lsB;
        #pragma unroll
        for (int kk = 0; kk < 2; ++kk) {
            bf16x8 a0 = *(const bf16x8*)(baseA + (wr +      fr) * 128 + kk * 64 + fk);
            bf16x8 a1 = *(const bf16x8*)(baseA + (wr + 16 + fr) * 128 + kk * 64 + fk);
            bf16x8 b0 = *(const bf16x8*)(baseB + (wc +      fr) * 128 + kk * 64 + fk);
            bf16x8 b1 = *(const bf16x8*)(baseB + (wc + 16 + fr) * 128 + kk * 64 + fk);
            acc[0][0] = __builtin_amdgcn_mfma_f32_16x16x32_bf16(a0, b0, acc[0][0], 0, 0, 0);
            acc[0][1] = __builtin_amdgcn_mfma_f32_16x16x32_bf16(a0, b1, acc[0][1], 0, 0, 0);
            acc[1][0] = __builtin_amdgcn_mfma_f32_16x16x32_bf16(a1, b0, acc[1][0], 0, 0, 0);
            acc[1][1] = __builtin_amdgcn_mfma_f32_16x16x32_bf16(a1, b1, acc[1][1], 0, 0, 0);
        }
        __syncthreads();
    }

    // epilogue: C/D layout col = lane&15, row = (lane>>4)*4 + j  [m89-verified]
    float* Pseg = P + seg * 524288;
    const int cr = brow + wr + (lane >> 4) * 4;
    const int cc = bcol + wc + fr;
    #pragma unroll
    for (int m = 0; m < 2; ++m)
        #pragma unroll
        for (int n = 0; n < 2; ++n)
            #pragma unroll
            for (int j = 0; j < 4; ++j)
                Pseg[(cr + m * 16 + j) * 1024 + cc + n * 16] = acc[m][n][j];
}

__global__ __launch_bounds__(256) void reduce_kernel(
    const float* __restrict__ P, float* __restrict__ out)
{
    const int idx = (blockIdx.x * 256 + threadIdx.x) * 4;
    float4 a = *(const float4*)(P + idx);
    float4 b = *(const float4*)(P + 524288 + idx);
    float4 c = *(const float4*)(P + 1048576 + idx);
    float4 d = *(const float4*)(P + 1572864 + idx);
    float4 o;
    o.x = a.x + b.x + c.x + d.x;
    o.y = a.y + b.y + c.y + d.y;
    o.z = a.z + b.z + c.z + d.z;
    o.w = a.w + b.w + c.w + d.w;
    *(float4*)(out + idx) = o;
}

extern "C" void kernel_launch(void* const* d_in, const int* in_sizes, int n_in,
                              void* d_out, int out_size, void* d_ws, size_t ws_size,
                              hipStream_t stream)
{
    const float* x   = (const float*)d_in[0];
    const float* cp0 = (const float*)d_in[1];
    const float* cp1 = (const float*)d_in[2];
    const float* cp2 = (const float*)d_in[3];
    const float* cp3 = (const float*)d_in[4];

    u16*   A = (u16*)d_ws;
    u16*   W = (u16*)((char*)d_ws + (4u << 20));
    float* P = (float*)((char*)d_ws + (12u << 20));
    float* out = (float*)d_out;

    prep_kernel<<<1536, 256, 0, stream>>>(x, cp0, cp1, cp2, cp3, A, W);
    gemm_kernel<<<dim3(16, 8, 4), 256, 0, stream>>>(A, W, P);
    reduce_kernel<<<512, 256, 0, stream>>>(P, out);
}

// Round 2
// 28.286 us; speedup vs baseline: 1.0378x; 1.0378x over previous
//
#include <hip/hip_runtime.h>

#define AS1 __attribute__((address_space(1)))
#define AS3 __attribute__((address_space(3)))

typedef unsigned short u16;
typedef __bf16 bf16x8 __attribute__((ext_vector_type(8)));
typedef float f32x4 __attribute__((ext_vector_type(4)));

// ws layout (28 MB total):
//   A: [4][512][1024]  bf16(u16)  @ 0        (4 MB)   A[seg][b][i] = b_seg(x[b][i])
//   W: [4][1024][1024] bf16(u16)  @ 4 MB     (8 MB)   W[seg][o][i] = bf16(cp_seg[o][i])
//   P: [8][512][1024]  f32        @ 12 MB    (16 MB)  split-K partials (seg-half slices)

__device__ __forceinline__ u16 f2bf(float f) {
    union { float f; unsigned int u; } v;
    v.f = f;
    unsigned int u = v.u;
    u += 0x7fffu + ((u >> 16) & 1u);   // RNE
    return (u16)(u >> 16);
}

__global__ __launch_bounds__(256) void prep_kernel(
    const float* __restrict__ x,
    const float* __restrict__ cp0, const float* __restrict__ cp1,
    const float* __restrict__ cp2, const float* __restrict__ cp3,
    u16* __restrict__ A, u16* __restrict__ W)
{
    const int bid = blockIdx.x;
    const int tid = threadIdx.x;
    if (bid < 1024) {
        const int idx = (bid * 256 + tid) * 4;            // [0, 1048576)
        const float* cps[4] = {cp0, cp1, cp2, cp3};
        #pragma unroll
        for (int seg = 0; seg < 4; ++seg) {
            float4 v = *(const float4*)(cps[seg] + idx);
            ushort4 o;
            o.x = f2bf(v.x); o.y = f2bf(v.y); o.z = f2bf(v.z); o.w = f2bf(v.w);
            *(ushort4*)(W + seg * 1048576 + idx) = o;
        }
    } else {
        const int idx = ((bid - 1024) * 256 + tid) * 4;   // [0, 524288)
        float4 v = *(const float4*)(x + idx);
        float vv[4] = {v.x, v.y, v.z, v.w};
        u16 q[4][4];
        #pragma unroll
        for (int j = 0; j < 4; ++j) {
            float xx = vv[j];
            float t = fminf(fabsf(xx), 1.0f);
            float s = 1.0f - t;
            q[0][j] = f2bf(s * s * s * xx);
            q[1][j] = f2bf(3.0f * s * s * t * xx);
            q[2][j] = f2bf(3.0f * s * t * t * xx);
            q[3][j] = f2bf(t * t * t * xx);
        }
        #pragma unroll
        for (int seg = 0; seg < 4; ++seg) {
            ushort4 o; o.x = q[seg][0]; o.y = q[seg][1]; o.z = q[seg][2]; o.w = q[seg][3];
            *(ushort4*)(A + seg * 524288 + idx) = o;
        }
    }
}

__device__ __forceinline__ void load16(const u16* g, u16* l) {
    __builtin_amdgcn_global_load_lds((const AS1 unsigned int*)g,
                                     (AS3 unsigned int*)l, 16, 0, 0);
}

// 128x128 tile, split-K=8 (seg-halves of 512), 512 threads (8 waves of 64x32).
// LDS tiles [128 rows][64 k] bf16, XOR-swizzled: 16B chunk (row, sub) holds
// global chunk (row, sub ^ (row&7)); reader XORs the same -> conflict-free.
__global__ __launch_bounds__(512) void gemm_kernel(
    const u16* __restrict__ A, const u16* __restrict__ W,
    float* __restrict__ P)
{
    __shared__ u16 lsA[2][128 * 64];
    __shared__ u16 lsB[2][128 * 64];

    const int tid  = threadIdx.x;
    const int lane = tid & 63;
    const int wid  = tid >> 6;

    const int bid  = blockIdx.x;          // 0..255
    const int nb   = bid & 7;             // N-block -> XCD affinity (bid % 8)
    const int mb   = (bid >> 3) & 3;      // M-block
    const int kz   = bid >> 5;            // K-slice 0..7
    const int seg  = kz >> 1;
    const int kbase = (kz & 1) * 512;
    const int brow = mb * 128;
    const int bcol = nb * 128;

    const u16* Ag = A + seg * 524288  + brow * 1024 + kbase;
    const u16* Wg = W + seg * 1048576 + bcol * 1024 + kbase;

    // staging: 1024 chunks of 16B per matrix tile; chunk c: row=c>>3, sub=c&7
    // global source pre-swizzled: e' = (sub ^ (row&7))*8 elems
    int goff[2], loff[2];
    #pragma unroll
    for (int j = 0; j < 2; ++j) {
        const int c   = tid + j * 512;
        const int row = c >> 3;
        const int ep  = ((c & 7) ^ (row & 7)) * 8;
        goff[j] = row * 1024 + ep;     // elems in global
        loff[j] = c * 8;               // elems in LDS (linear dest)
    }

    // wave sub-tile: 2(M) x 4(N) wave grid; each wave 64x32
    const int wr = (wid >> 2) * 64;
    const int wc = (wid & 3) * 32;
    const int fr = lane & 15;
    // per-kk swizzled byte offset within a row (row&7 == lane&7 for all frags)
    int ofs[2];
    ofs[0] = (((lane >> 4)    ) ^ (lane & 7)) * 16;
    ofs[1] = (((lane >> 4) + 4) ^ (lane & 7)) * 16;

    f32x4 acc[4][2] = {};

    // prologue: stage tile 0
    #pragma unroll
    for (int j = 0; j < 2; ++j) {
        load16(Ag + goff[j], &lsA[0][loff[j]]);
        load16(Wg + goff[j], &lsB[0][loff[j]]);
    }
    __syncthreads();

    for (int kt = 0; kt < 8; ++kt) {
        const int buf = kt & 1;
        if (kt < 7) {
            const int k0 = (kt + 1) * 64;
            #pragma unroll
            for (int j = 0; j < 2; ++j) {
                load16(Ag + k0 + goff[j], &lsA[buf ^ 1][loff[j]]);
                load16(Wg + k0 + goff[j], &lsB[buf ^ 1][loff[j]]);
            }
        }
        const char* bA = (const char*)lsA[buf];
        const char* bB = (const char*)lsB[buf];
        #pragma unroll
        for (int kk = 0; kk < 2; ++kk) {
            bf16x8 a[4], b[2];
            #pragma unroll
            for (int m = 0; m < 4; ++m)
                a[m] = *(const bf16x8*)(bA + (wr + m * 16 + fr) * 128 + ofs[kk]);
            #pragma unroll
            for (int n = 0; n < 2; ++n)
                b[n] = *(const bf16x8*)(bB + (wc + n * 16 + fr) * 128 + ofs[kk]);
            #pragma unroll
            for (int m = 0; m < 4; ++m)
                #pragma unroll
                for (int n = 0; n < 2; ++n)
                    acc[m][n] = __builtin_amdgcn_mfma_f32_16x16x32_bf16(
                        a[m], b[n], acc[m][n], 0, 0, 0);
        }
        __syncthreads();   // drains vmcnt(0): next tile landed; buffers swap safe
    }

    // epilogue: C/D layout col = lane&15, row = (lane>>4)*4 + j  [m89-verified]
    float* Pk = P + kz * 524288;
    const int cr0 = brow + wr + (lane >> 4) * 4;
    const int cc0 = bcol + wc + fr;
    #pragma unroll
    for (int m = 0; m < 4; ++m)
        #pragma unroll
        for (int n = 0; n < 2; ++n)
            #pragma unroll
            for (int j = 0; j < 4; ++j)
                Pk[(cr0 + m * 16 + j) * 1024 + cc0 + n * 16] = acc[m][n][j];
}

__global__ __launch_bounds__(256) void reduce_kernel(
    const float* __restrict__ P, float* __restrict__ out)
{
    const int idx = (blockIdx.x * 256 + threadIdx.x) * 4;
    float4 s = *(const float4*)(P + idx);
    #pragma unroll
    for (int z = 1; z < 8; ++z) {
        float4 v = *(const float4*)(P + z * 524288 + idx);
        s.x += v.x; s.y += v.y; s.z += v.z; s.w += v.w;
    }
    *(float4*)(out + idx) = s;
}

extern "C" void kernel_launch(void* const* d_in, const int* in_sizes, int n_in,
                              void* d_out, int out_size, void* d_ws, size_t ws_size,
                              hipStream_t stream)
{
    const float* x   = (const float*)d_in[0];
    const float* cp0 = (const float*)d_in[1];
    const float* cp1 = (const float*)d_in[2];
    const float* cp2 = (const float*)d_in[3];
    const float* cp3 = (const float*)d_in[4];

    u16*   A = (u16*)d_ws;
    u16*   W = (u16*)((char*)d_ws + (4u << 20));
    float* P = (float*)((char*)d_ws + (12u << 20));
    float* out = (float*)d_out;

    prep_kernel<<<1536, 256, 0, stream>>>(x, cp0, cp1, cp2, cp3, A, W);
    gemm_kernel<<<256, 512, 0, stream>>>(A, W, P);
    reduce_kernel<<<512, 256, 0, stream>>>(P, out);
}